// Round 6
// baseline (409.771 us; speedup 1.0000x reference)
//
#include <hip/hip_runtime.h>

// LocEncoder fused, round 16 (4th resubmit — r2-r5 benches were GPU-
// acquisition timeouts, no data): kill k3's p1/p2 via order-free global
// bucket scatter.
//
// Post-mortem r15: LDS-w + quad windows REGRESSED k3 (80->90us, VALUBusy
// 50->43%) -> p4 gather latency was not the bottleneck. The 110MB FETCH
// signature is p2's random 4B gather from blockSorted (+ 9-step binary
// search per edge). Max-aggregation is ORDER-INVARIANT, so the two-level
// partition is unnecessary: scatter edges directly into per-bucket
// fixed-capacity slabs (CAP=1280 == old SCAP2 truncation semantics) with
// device atomicAdd cursors. k3 reads its bucket CONTIGUOUSLY; p1 (run
// table + scans) and p2 (binary search + random gather) are deleted.
// p4 reverted verbatim to the round-14 pair structure (known 80us).
//
//   h1 = relu(u[src] - w[dst]),  u/w precomputed fp16 (round-5 algebra)
//
//  k1 precompute (512 x 256): wave-per-2-nodes VALU -> u16,w16 [N,64] fp16
//  k2 scatter (1563 x 256): ei int4 read -> b=dst>>6,
//      p=atomicAdd(gcnt[b]) -> sortedG[b*CAP+p] = src<<6|dlow
//  k3 aggregate (1563 x 256, ~11 KB LDS): contiguous slab read + 64-bin
//      histogram, scan -> LDS counting sort (sortedL), then per-wave 16
//      nodes as PAIRS, 16-row f16 MFMA tiles, register vmax, shuffle
//      reduce, one coalesced store per node.

#define N_NODES 100000
#define N_EDGES 1600000
#define NB2  1563     // dst buckets (dst >> 6), 64 nodes each
#define CAP  1280     // slab capacity per bucket (mean 1024, +8 sigma)

typedef _Float16 half8 __attribute__((ext_vector_type(8)));
typedef float float4v __attribute__((ext_vector_type(4)));

__device__ inline int wave_incl_scan(int v, int lane) {
#pragma unroll
    for (int d = 1; d < 64; d <<= 1) {
        const int t = __shfl_up(v, d);
        if (lane >= d) v += t;
    }
    return v;
}

// ---- k1: u/w precompute, 2 nodes per wave-iteration (ILP) ----
__global__ __launch_bounds__(256) void precompute_kernel(
    const float* __restrict__ x, const float* __restrict__ pos,
    const float* __restrict__ W1, const float* __restrict__ b1,
    _Float16* __restrict__ u16, _Float16* __restrict__ w16)
{
    const int lane = threadIdx.x & 63;
    float w1c[16];
#pragma unroll
    for (int k = 0; k < 16; ++k) w1c[k] = W1[k * 64 + lane];
    const float b1c = b1[lane];

    const int waveId = blockIdx.x * 4 + (threadIdx.x >> 6);
    const int step   = 512 * 4 * 2;

    for (int nd = waveId * 2; nd < N_NODES; nd += step) {
        const int nA = nd, nB = nd + 1;  // N_NODES even -> nB always valid
        float mA = 0.f, mB = 0.f;
        if (lane < 13) {
            mA = x[nA * 13 + lane];
            mB = x[nB * 13 + lane];
        } else if (lane < 16) {
            mA = pos[nA * 3 + (lane - 13)];
            mB = pos[nB * 3 + (lane - 13)];
        }

        float aA = b1c, wA = 0.f, aB = b1c, wB = 0.f;
#pragma unroll
        for (int k = 0; k < 13; ++k) {
            aA = fmaf(__shfl(mA, k), w1c[k], aA);
            aB = fmaf(__shfl(mB, k), w1c[k], aB);
        }
#pragma unroll
        for (int k = 13; k < 16; ++k) {
            const float pA = __shfl(mA, k), pB = __shfl(mB, k);
            aA = fmaf(pA, w1c[k], aA);  wA = fmaf(pA, w1c[k], wA);
            aB = fmaf(pB, w1c[k], aB);  wB = fmaf(pB, w1c[k], wB);
        }
        u16[nA * 64 + lane] = (_Float16)aA;
        w16[nA * 64 + lane] = (_Float16)wA;
        u16[nB * 64 + lane] = (_Float16)aB;
        w16[nB * 64 + lane] = (_Float16)wB;
    }
}

// ---- k2: direct bucket scatter (order-free; max-agg is order-invariant) ----
__global__ __launch_bounds__(256) void scatter_kernel(
    const int* __restrict__ ei,        // [2,E]
    int* __restrict__ gcnt,            // [NB2] zeroed before launch
    int* __restrict__ sortedG)         // [NB2][CAP] packed src<<6|dlow
{
    const int base = (blockIdx.x * 256 + threadIdx.x) * 4;
    if (base >= N_EDGES) return;       // N_EDGES % 4 == 0 -> whole int4 valid
    const int4 s4 = *(const int4*)(ei + base);
    const int4 d4 = *(const int4*)(ei + N_EDGES + base);
    int b, p;
    b = d4.x >> 6; p = atomicAdd(&gcnt[b], 1);
    if (p < CAP) sortedG[b * CAP + p] = (s4.x << 6) | (d4.x & 63);
    b = d4.y >> 6; p = atomicAdd(&gcnt[b], 1);
    if (p < CAP) sortedG[b * CAP + p] = (s4.y << 6) | (d4.y & 63);
    b = d4.z >> 6; p = atomicAdd(&gcnt[b], 1);
    if (p < CAP) sortedG[b * CAP + p] = (s4.z << 6) | (d4.z & 63);
    b = d4.w >> 6; p = atomicAdd(&gcnt[b], 1);
    if (p < CAP) sortedG[b * CAP + p] = (s4.w << 6) | (d4.w & 63);
}

// ---- k3: bucket aggregate — LDS counting sort + fp16 MFMA register-max ----
__global__ __launch_bounds__(256, 4) void aggregate_kernel(
    const _Float16* __restrict__ u16,  // [N,64] fp16
    const _Float16* __restrict__ w16,  // [N,64] fp16
    const float* __restrict__ W2,      // [64,64]
    const float* __restrict__ b2,      // [64]
    const int*   __restrict__ gcnt,    // [NB2]
    const int*   __restrict__ sortedG, // [NB2][CAP]
    float*       __restrict__ out)     // [N,64]
{
    __shared__ int staged[CAP];         // 5,120 B packed edges
    __shared__ int sortedL[CAP];        // 5,120 B src, grouped by node
    __shared__ int hist[64], nstart[64], hoff[64];

    const int tid  = threadIdx.x;
    const int lane = tid & 63;
    const int wv   = tid >> 6;
    const int q = lane >> 4, n = lane & 15;
    const int b = blockIdx.x;
    const int node0 = b * 64;

    // W2 B-frags (fp16) + bias
    half8 w2f[2][4];
#pragma unroll
    for (int s = 0; s < 2; ++s)
#pragma unroll
        for (int t = 0; t < 4; ++t)
#pragma unroll
            for (int j = 0; j < 8; ++j)
                w2f[s][t][j] = (_Float16)W2[(s * 32 + q * 8 + j) * 64 + (n + 16 * t)];
    float b2c[4];
#pragma unroll
    for (int t = 0; t < 4; ++t) b2c[t] = b2[n + 16 * t];

    if (tid < 64) hist[tid] = 0;
    __syncthreads();

    const int cnt = gcnt[b];
    const int T = cnt < CAP ? cnt : CAP;

    // p2: contiguous slab read -> staged + 64-bin node histogram
    const int nI4 = (T + 3) >> 2;
    for (int i4 = tid; i4 < nI4; i4 += 256) {
        const int4 v = *(const int4*)(sortedG + b * CAP + i4 * 4);
        const int e0 = i4 * 4;
        if (e0 + 0 < T) { staged[e0 + 0] = v.x; atomicAdd(&hist[v.x & 63], 1); }
        if (e0 + 1 < T) { staged[e0 + 1] = v.y; atomicAdd(&hist[v.y & 63], 1); }
        if (e0 + 2 < T) { staged[e0 + 2] = v.z; atomicAdd(&hist[v.z & 63], 1); }
        if (e0 + 3 < T) { staged[e0 + 3] = v.w; atomicAdd(&hist[v.w & 63], 1); }
    }
    __syncthreads();

    // p3: scan hist(64) by wave 0 -> nstart; counting-sort into sortedL
    if (wv == 0) {
        const int v = hist[lane];
        const int inc = wave_incl_scan(v, lane);
        nstart[lane] = inc - v;
        hoff[lane]   = inc - v;
    }
    __syncthreads();
    for (int i = tid; i < T; i += 256) {
        const int w = staged[i];
        const int p = atomicAdd(&hoff[w & 63], 1);
        sortedL[p] = w >> 6;
    }
    __syncthreads();

    // p4: per-node register-max fp16 MFMA (pairs; gathers in flight first)
    const half8 zero8 = {0, 0, 0, 0, 0, 0, 0, 0};

    auto compute = [&](int node, int2 sd, int src,
                       half8 ulo, half8 uhi, half8 wl, half8 wh) {
        float vmax[4] = {0.f, 0.f, 0.f, 0.f};  // 0-init == relu + empty=0
        int base = 0;
        while (true) {
            const int rows = (sd.y - base) < 16 ? (sd.y - base) : 16;
            if (rows > 0) {
                // packed: v_pk_add_f16 (sub) + v_pk_max_f16 (relu)
                const half8 alo = __builtin_elementwise_max(ulo - wl, zero8);
                const half8 ahi = __builtin_elementwise_max(uhi - wh, zero8);
                float4v c2[4];
#pragma unroll
                for (int t = 0; t < 4; ++t) {
                    c2[t] = __builtin_amdgcn_mfma_f32_16x16x32_f16(
                        alo, w2f[0][t], (float4v){0.f, 0.f, 0.f, 0.f}, 0, 0, 0);
                    c2[t] = __builtin_amdgcn_mfma_f32_16x16x32_f16(
                        ahi, w2f[1][t], c2[t], 0, 0, 0);
                }
#pragma unroll
                for (int r = 0; r < 4; ++r) {
                    const int row = q * 4 + r;
#pragma unroll
                    for (int t = 0; t < 4; ++t) {
                        const float v = c2[t][r] + b2c[t];
                        if (row < rows) vmax[t] = fmaxf(vmax[t], v);
                    }
                }
            }
            base += 16;
            if (base >= sd.y) break;
            const int r2 = (sd.y - base) < 16 ? (sd.y - base) : 16;
            src = (n < r2) ? sortedL[sd.x + base + n] : 0;
            ulo = *(const half8*)(u16 + src * 64 + q * 8);
            uhi = *(const half8*)(u16 + src * 64 + 32 + q * 8);
        }
#pragma unroll
        for (int t = 0; t < 4; ++t) {
            vmax[t] = fmaxf(vmax[t], __shfl_xor(vmax[t], 16));
            vmax[t] = fmaxf(vmax[t], __shfl_xor(vmax[t], 32));
        }
        float v = vmax[0];
        v = (q == 1) ? vmax[1] : v;
        v = (q == 2) ? vmax[2] : v;
        v = (q == 3) ? vmax[3] : v;
        if (node < N_NODES) out[node * 64 + lane] = v;
    };

    const int nlbase = wv * 16;
#pragma unroll 1
    for (int g = 0; g < 16; g += 2) {
        const int nlA = nlbase + g, nlB = nlA + 1;
        const int nA = node0 + nlA, nB = node0 + nlB;
        const int2 sdA = {nstart[nlA], hist[nlA]};
        const int2 sdB = {nstart[nlB], hist[nlB]};
        const int nAc = nA < (N_NODES - 1) ? nA : (N_NODES - 1);  // clamp loads
        const int nBc = nB < (N_NODES - 1) ? nB : (N_NODES - 1);

        const int rA = sdA.y < 16 ? sdA.y : 16;
        const int rB = sdB.y < 16 ? sdB.y : 16;
        const int srcA = (n < rA) ? sortedL[sdA.x + n] : 0;
        const int srcB = (n < rB) ? sortedL[sdB.x + n] : 0;

        // both nodes' gathers in flight before either compute
        const half8 ulA = *(const half8*)(u16 + srcA * 64 + q * 8);
        const half8 uhA = *(const half8*)(u16 + srcA * 64 + 32 + q * 8);
        const half8 wlA = *(const half8*)(w16 + nAc * 64 + q * 8);
        const half8 whA = *(const half8*)(w16 + nAc * 64 + 32 + q * 8);
        const half8 ulB = *(const half8*)(u16 + srcB * 64 + q * 8);
        const half8 uhB = *(const half8*)(u16 + srcB * 64 + 32 + q * 8);
        const half8 wlB = *(const half8*)(w16 + nBc * 64 + q * 8);
        const half8 whB = *(const half8*)(w16 + nBc * 64 + 32 + q * 8);

        compute(nA, sdA, srcA, ulA, uhA, wlA, whA);
        compute(nB, sdB, srcB, ulB, uhB, wlB, whB);
    }
}

extern "C" void kernel_launch(void* const* d_in, const int* in_sizes, int n_in,
                              void* d_out, int out_size, void* d_ws, size_t ws_size,
                              hipStream_t stream) {
    const float* x   = (const float*)d_in[0];
    const float* pos = (const float*)d_in[1];
    const float* W1  = (const float*)d_in[2];
    const float* b1  = (const float*)d_in[3];
    const float* W2  = (const float*)d_in[4];
    const float* b2  = (const float*)d_in[5];
    const int*   ei  = (const int*)d_in[6];

    char* ws = (char*)d_ws;
    int* gcnt    = (int*)(ws + 0);              // 6,252 B (padded to 8,192)
    int* sortedG = (int*)(ws + 8192);           // 8,002,560 B [NB2][CAP]
    _Float16* u16 = (_Float16*)(ws + 8010752);  // 12.8 MB
    _Float16* w16 = (_Float16*)(ws + 20810752); // 12.8 MB  (end ~33.6 MB)

    hipMemsetAsync(gcnt, 0, NB2 * sizeof(int), stream);
    precompute_kernel<<<512, 256, 0, stream>>>(x, pos, W1, b1, u16, w16);
    scatter_kernel<<<1563, 256, 0, stream>>>(ei, gcnt, sortedG);
    aggregate_kernel<<<NB2, 256, 0, stream>>>(
        u16, w16, W2, b2, gcnt, sortedG, (float*)d_out);
}

// Round 7
// 188.505 us; speedup vs baseline: 2.1738x; 2.1738x over previous
//
#include <hip/hip_runtime.h>

// LocEncoder fused, round 17: fix scatter atomic contention via
// hierarchical reservation (two-pass radix partition into global slabs).
//
// Post-mortem r16: direct per-edge atomic scatter = 241us steady
// (VALUBusy 0.2%): 1.6M returning atomics over 1563 words ~= 1024
// serialized same-address L2 atomics per word (~150-200us), plus 78MB
// write traffic from random 4B stores dirtying 64B lines. Fix: each of
// 125 blocks owns 12800 edges; (A) LDS histogram; (B) ONE global
// atomicAdd per (block,bucket) reserves a contiguous range (<=125
// atomics/address, 195K total); (C) re-read edges (L2-hot) and scatter
// via LDS cursors -> per-block contiguous runs that L2 write-merges.
// k3's contiguous-slab read is kept (r16 positive: aggregate fell out
// of the top-5, i.e. < 241us).
//
//   h1 = relu(u[src] - w[dst]),  u/w precomputed fp16 (round-5 algebra)
//
//  k1 precompute (512 x 256): wave-per-2-nodes VALU -> u16,w16 [N,64] fp16
//  k2 scatter (125 x 512, 6.3 KB LDS): hist -> reserve -> scatter
//  k3 aggregate (1563 x 256, ~11 KB LDS): contiguous slab read + 64-bin
//      histogram, scan -> LDS counting sort (sortedL), then per-wave 16
//      nodes as PAIRS, 16-row f16 MFMA tiles, register vmax, shuffle
//      reduce, one coalesced store per node.

#define N_NODES 100000
#define N_EDGES 1600000
#define NB2  1563     // dst buckets (dst >> 6), 64 nodes each
#define CAP  1280     // slab capacity per bucket (mean 1024, +8 sigma)
#define SGRID 125     // scatter blocks
#define SEPB 12800    // edges per scatter block (125*12800 = 1.6M exactly)

typedef _Float16 half8 __attribute__((ext_vector_type(8)));
typedef float float4v __attribute__((ext_vector_type(4)));

__device__ inline int wave_incl_scan(int v, int lane) {
#pragma unroll
    for (int d = 1; d < 64; d <<= 1) {
        const int t = __shfl_up(v, d);
        if (lane >= d) v += t;
    }
    return v;
}

// ---- k1: u/w precompute, 2 nodes per wave-iteration (ILP) ----
__global__ __launch_bounds__(256) void precompute_kernel(
    const float* __restrict__ x, const float* __restrict__ pos,
    const float* __restrict__ W1, const float* __restrict__ b1,
    _Float16* __restrict__ u16, _Float16* __restrict__ w16)
{
    const int lane = threadIdx.x & 63;
    float w1c[16];
#pragma unroll
    for (int k = 0; k < 16; ++k) w1c[k] = W1[k * 64 + lane];
    const float b1c = b1[lane];

    const int waveId = blockIdx.x * 4 + (threadIdx.x >> 6);
    const int step   = 512 * 4 * 2;

    for (int nd = waveId * 2; nd < N_NODES; nd += step) {
        const int nA = nd, nB = nd + 1;  // N_NODES even -> nB always valid
        float mA = 0.f, mB = 0.f;
        if (lane < 13) {
            mA = x[nA * 13 + lane];
            mB = x[nB * 13 + lane];
        } else if (lane < 16) {
            mA = pos[nA * 3 + (lane - 13)];
            mB = pos[nB * 3 + (lane - 13)];
        }

        float aA = b1c, wA = 0.f, aB = b1c, wB = 0.f;
#pragma unroll
        for (int k = 0; k < 13; ++k) {
            aA = fmaf(__shfl(mA, k), w1c[k], aA);
            aB = fmaf(__shfl(mB, k), w1c[k], aB);
        }
#pragma unroll
        for (int k = 13; k < 16; ++k) {
            const float pA = __shfl(mA, k), pB = __shfl(mB, k);
            aA = fmaf(pA, w1c[k], aA);  wA = fmaf(pA, w1c[k], wA);
            aB = fmaf(pB, w1c[k], aB);  wB = fmaf(pB, w1c[k], wB);
        }
        u16[nA * 64 + lane] = (_Float16)aA;
        w16[nA * 64 + lane] = (_Float16)wA;
        u16[nB * 64 + lane] = (_Float16)aB;
        w16[nB * 64 + lane] = (_Float16)wB;
    }
}

// ---- k2: hierarchical reservation scatter ----
__global__ __launch_bounds__(512) void scatter_kernel(
    const int* __restrict__ ei,        // [2,E]
    int* __restrict__ gcnt,            // [NB2] zeroed before launch
    int* __restrict__ sortedG)         // [NB2][CAP] packed src<<6|dlow
{
    __shared__ int hist[NB2];          // 6,252 B: counts -> then cursors

    const int tid = threadIdx.x;
    const int e0  = blockIdx.x * SEPB; // SEPB divides N_EDGES exactly
    const int nI4 = SEPB >> 2;         // 3200 int4 per block

    for (int i = tid; i < NB2; i += 512) hist[i] = 0;
    __syncthreads();

    // pass A: LDS histogram of this block's 12800 dsts
    for (int i4 = tid; i4 < nI4; i4 += 512) {
        const int4 d4 = *(const int4*)(ei + N_EDGES + e0 + i4 * 4);
        atomicAdd(&hist[d4.x >> 6], 1);
        atomicAdd(&hist[d4.y >> 6], 1);
        atomicAdd(&hist[d4.z >> 6], 1);
        atomicAdd(&hist[d4.w >> 6], 1);
    }
    __syncthreads();

    // pass B: one global reservation per touched bucket; hist becomes cursor
    for (int i = tid; i < NB2; i += 512) {
        const int cnt = hist[i];
        hist[i] = (cnt > 0) ? atomicAdd(&gcnt[i], cnt) : 0;
    }
    __syncthreads();

    // pass C: re-read (L2-hot) and scatter into reserved contiguous runs
    for (int i4 = tid; i4 < nI4; i4 += 512) {
        const int4 s4 = *(const int4*)(ei + e0 + i4 * 4);
        const int4 d4 = *(const int4*)(ei + N_EDGES + e0 + i4 * 4);
        int b, p;
        b = d4.x >> 6; p = atomicAdd(&hist[b], 1);
        if (p < CAP) sortedG[b * CAP + p] = (s4.x << 6) | (d4.x & 63);
        b = d4.y >> 6; p = atomicAdd(&hist[b], 1);
        if (p < CAP) sortedG[b * CAP + p] = (s4.y << 6) | (d4.y & 63);
        b = d4.z >> 6; p = atomicAdd(&hist[b], 1);
        if (p < CAP) sortedG[b * CAP + p] = (s4.z << 6) | (d4.z & 63);
        b = d4.w >> 6; p = atomicAdd(&hist[b], 1);
        if (p < CAP) sortedG[b * CAP + p] = (s4.w << 6) | (d4.w & 63);
    }
}

// ---- k3: bucket aggregate — LDS counting sort + fp16 MFMA register-max ----
__global__ __launch_bounds__(256, 4) void aggregate_kernel(
    const _Float16* __restrict__ u16,  // [N,64] fp16
    const _Float16* __restrict__ w16,  // [N,64] fp16
    const float* __restrict__ W2,      // [64,64]
    const float* __restrict__ b2,      // [64]
    const int*   __restrict__ gcnt,    // [NB2]
    const int*   __restrict__ sortedG, // [NB2][CAP]
    float*       __restrict__ out)     // [N,64]
{
    __shared__ int staged[CAP];         // 5,120 B packed edges
    __shared__ int sortedL[CAP];        // 5,120 B src, grouped by node
    __shared__ int hist[64], nstart[64], hoff[64];

    const int tid  = threadIdx.x;
    const int lane = tid & 63;
    const int wv   = tid >> 6;
    const int q = lane >> 4, n = lane & 15;
    const int b = blockIdx.x;
    const int node0 = b * 64;

    // W2 B-frags (fp16) + bias
    half8 w2f[2][4];
#pragma unroll
    for (int s = 0; s < 2; ++s)
#pragma unroll
        for (int t = 0; t < 4; ++t)
#pragma unroll
            for (int j = 0; j < 8; ++j)
                w2f[s][t][j] = (_Float16)W2[(s * 32 + q * 8 + j) * 64 + (n + 16 * t)];
    float b2c[4];
#pragma unroll
    for (int t = 0; t < 4; ++t) b2c[t] = b2[n + 16 * t];

    if (tid < 64) hist[tid] = 0;
    __syncthreads();

    const int cnt = gcnt[b];
    const int T = cnt < CAP ? cnt : CAP;

    // p2: contiguous slab read -> staged + 64-bin node histogram
    const int nI4 = (T + 3) >> 2;
    for (int i4 = tid; i4 < nI4; i4 += 256) {
        const int4 v = *(const int4*)(sortedG + b * CAP + i4 * 4);
        const int e0 = i4 * 4;
        if (e0 + 0 < T) { staged[e0 + 0] = v.x; atomicAdd(&hist[v.x & 63], 1); }
        if (e0 + 1 < T) { staged[e0 + 1] = v.y; atomicAdd(&hist[v.y & 63], 1); }
        if (e0 + 2 < T) { staged[e0 + 2] = v.z; atomicAdd(&hist[v.z & 63], 1); }
        if (e0 + 3 < T) { staged[e0 + 3] = v.w; atomicAdd(&hist[v.w & 63], 1); }
    }
    __syncthreads();

    // p3: scan hist(64) by wave 0 -> nstart; counting-sort into sortedL
    if (wv == 0) {
        const int v = hist[lane];
        const int inc = wave_incl_scan(v, lane);
        nstart[lane] = inc - v;
        hoff[lane]   = inc - v;
    }
    __syncthreads();
    for (int i = tid; i < T; i += 256) {
        const int w = staged[i];
        const int p = atomicAdd(&hoff[w & 63], 1);
        sortedL[p] = w >> 6;
    }
    __syncthreads();

    // p4: per-node register-max fp16 MFMA (pairs; gathers in flight first)
    const half8 zero8 = {0, 0, 0, 0, 0, 0, 0, 0};

    auto compute = [&](int node, int2 sd, int src,
                       half8 ulo, half8 uhi, half8 wl, half8 wh) {
        float vmax[4] = {0.f, 0.f, 0.f, 0.f};  // 0-init == relu + empty=0
        int base = 0;
        while (true) {
            const int rows = (sd.y - base) < 16 ? (sd.y - base) : 16;
            if (rows > 0) {
                // packed: v_pk_add_f16 (sub) + v_pk_max_f16 (relu)
                const half8 alo = __builtin_elementwise_max(ulo - wl, zero8);
                const half8 ahi = __builtin_elementwise_max(uhi - wh, zero8);
                float4v c2[4];
#pragma unroll
                for (int t = 0; t < 4; ++t) {
                    c2[t] = __builtin_amdgcn_mfma_f32_16x16x32_f16(
                        alo, w2f[0][t], (float4v){0.f, 0.f, 0.f, 0.f}, 0, 0, 0);
                    c2[t] = __builtin_amdgcn_mfma_f32_16x16x32_f16(
                        ahi, w2f[1][t], c2[t], 0, 0, 0);
                }
#pragma unroll
                for (int r = 0; r < 4; ++r) {
                    const int row = q * 4 + r;
#pragma unroll
                    for (int t = 0; t < 4; ++t) {
                        const float v = c2[t][r] + b2c[t];
                        if (row < rows) vmax[t] = fmaxf(vmax[t], v);
                    }
                }
            }
            base += 16;
            if (base >= sd.y) break;
            const int r2 = (sd.y - base) < 16 ? (sd.y - base) : 16;
            src = (n < r2) ? sortedL[sd.x + base + n] : 0;
            ulo = *(const half8*)(u16 + src * 64 + q * 8);
            uhi = *(const half8*)(u16 + src * 64 + 32 + q * 8);
        }
#pragma unroll
        for (int t = 0; t < 4; ++t) {
            vmax[t] = fmaxf(vmax[t], __shfl_xor(vmax[t], 16));
            vmax[t] = fmaxf(vmax[t], __shfl_xor(vmax[t], 32));
        }
        float v = vmax[0];
        v = (q == 1) ? vmax[1] : v;
        v = (q == 2) ? vmax[2] : v;
        v = (q == 3) ? vmax[3] : v;
        if (node < N_NODES) out[node * 64 + lane] = v;
    };

    const int nlbase = wv * 16;
#pragma unroll 1
    for (int g = 0; g < 16; g += 2) {
        const int nlA = nlbase + g, nlB = nlA + 1;
        const int nA = node0 + nlA, nB = node0 + nlB;
        const int2 sdA = {nstart[nlA], hist[nlA]};
        const int2 sdB = {nstart[nlB], hist[nlB]};
        const int nAc = nA < (N_NODES - 1) ? nA : (N_NODES - 1);  // clamp loads
        const int nBc = nB < (N_NODES - 1) ? nB : (N_NODES - 1);

        const int rA = sdA.y < 16 ? sdA.y : 16;
        const int rB = sdB.y < 16 ? sdB.y : 16;
        const int srcA = (n < rA) ? sortedL[sdA.x + n] : 0;
        const int srcB = (n < rB) ? sortedL[sdB.x + n] : 0;

        // both nodes' gathers in flight before either compute
        const half8 ulA = *(const half8*)(u16 + srcA * 64 + q * 8);
        const half8 uhA = *(const half8*)(u16 + srcA * 64 + 32 + q * 8);
        const half8 wlA = *(const half8*)(w16 + nAc * 64 + q * 8);
        const half8 whA = *(const half8*)(w16 + nAc * 64 + 32 + q * 8);
        const half8 ulB = *(const half8*)(u16 + srcB * 64 + q * 8);
        const half8 uhB = *(const half8*)(u16 + srcB * 64 + 32 + q * 8);
        const half8 wlB = *(const half8*)(w16 + nBc * 64 + q * 8);
        const half8 whB = *(const half8*)(w16 + nBc * 64 + 32 + q * 8);

        compute(nA, sdA, srcA, ulA, uhA, wlA, whA);
        compute(nB, sdB, srcB, ulB, uhB, wlB, whB);
    }
}

extern "C" void kernel_launch(void* const* d_in, const int* in_sizes, int n_in,
                              void* d_out, int out_size, void* d_ws, size_t ws_size,
                              hipStream_t stream) {
    const float* x   = (const float*)d_in[0];
    const float* pos = (const float*)d_in[1];
    const float* W1  = (const float*)d_in[2];
    const float* b1  = (const float*)d_in[3];
    const float* W2  = (const float*)d_in[4];
    const float* b2  = (const float*)d_in[5];
    const int*   ei  = (const int*)d_in[6];

    char* ws = (char*)d_ws;
    int* gcnt    = (int*)(ws + 0);              // 6,252 B (padded to 8,192)
    int* sortedG = (int*)(ws + 8192);           // 8,002,560 B [NB2][CAP]
    _Float16* u16 = (_Float16*)(ws + 8010752);  // 12.8 MB
    _Float16* w16 = (_Float16*)(ws + 20810752); // 12.8 MB  (end ~33.6 MB)

    hipMemsetAsync(gcnt, 0, NB2 * sizeof(int), stream);
    precompute_kernel<<<512, 256, 0, stream>>>(x, pos, W1, b1, u16, w16);
    scatter_kernel<<<SGRID, 512, 0, stream>>>(ei, gcnt, sortedG);
    aggregate_kernel<<<NB2, 256, 0, stream>>>(
        u16, w16, W2, b2, gcnt, sortedG, (float*)d_out);
}

// Round 8
// 178.892 us; speedup vs baseline: 2.2906x; 1.0537x over previous
//
#include <hip/hip_runtime.h>

// LocEncoder fused, round 18: fuse precompute + scatter into one kernel.
//
// Post-mortem r17: reservation scatter worked (scatter fell out of top-5,
// k3 80.4->71.6us, FETCH 110->85MB). But total is 188.5us with k3=71.6:
// ~117us hides in memset+k1+k2, each <71us, plausibly ~55us apiece. Both
// are latency-bound at partial occupancy on DISJOINT resources (k1:
// VALU/shfl + narrow stores; k2: atomics + scattered stores, 125 blocks
// = 4 waves/CU). They are data-independent -> fuse into one dispatch:
// 125 scatter-role blocks + 256 precompute-role blocks, 512 thr each.
// Co-residency hides each one's latency under the other: t1+t2 -> max.
// k3 untouched (clean A/B). Fused kernel will show in top-5 -> finally
// measures the k1+k2 cost directly.
//
//   h1 = relu(u[src] - w[dst]),  u/w precomputed fp16 (round-5 algebra)
//
//  k12 prep (381 x 512): bid<125 -> scatter role (hist 6.3KB LDS ->
//      global reservation -> cursor scatter); else precompute role
//      (wave-per-2-nodes VALU -> u16,w16 [N,64] fp16)
//  k3 aggregate (1563 x 256, ~11 KB LDS): contiguous slab read + 64-bin
//      histogram, scan -> LDS counting sort (sortedL), then per-wave 16
//      nodes as PAIRS, 16-row f16 MFMA tiles, register vmax, shuffle
//      reduce, one coalesced store per node.

#define N_NODES 100000
#define N_EDGES 1600000
#define NB2  1563     // dst buckets (dst >> 6), 64 nodes each
#define CAP  1280     // slab capacity per bucket (mean 1024, +8 sigma)
#define SGRID 125     // scatter-role blocks
#define SEPB 12800    // edges per scatter block (125*12800 = 1.6M exactly)
#define PGRID 256     // precompute-role blocks (x 8 waves = 2048 waves)

typedef _Float16 half8 __attribute__((ext_vector_type(8)));
typedef float float4v __attribute__((ext_vector_type(4)));

__device__ inline int wave_incl_scan(int v, int lane) {
#pragma unroll
    for (int d = 1; d < 64; d <<= 1) {
        const int t = __shfl_up(v, d);
        if (lane >= d) v += t;
    }
    return v;
}

// ---- k12: fused scatter + precompute (data-independent roles) ----
__global__ __launch_bounds__(512) void prep_kernel(
    const float* __restrict__ x, const float* __restrict__ pos,
    const float* __restrict__ W1, const float* __restrict__ b1,
    const int* __restrict__ ei,        // [2,E]
    int* __restrict__ gcnt,            // [NB2] zeroed before launch
    int* __restrict__ sortedG,         // [NB2][CAP] packed src<<6|dlow
    _Float16* __restrict__ u16, _Float16* __restrict__ w16)
{
    __shared__ int hist[NB2];          // 6,252 B (scatter role only)

    const int bid = blockIdx.x;
    const int tid = threadIdx.x;

    if (bid < SGRID) {
        // ---- scatter role: hist -> reserve -> cursor scatter ----
        const int e0  = bid * SEPB;
        const int nI4 = SEPB >> 2;     // 3200 int4

        for (int i = tid; i < NB2; i += 512) hist[i] = 0;
        __syncthreads();

        for (int i4 = tid; i4 < nI4; i4 += 512) {
            const int4 d4 = *(const int4*)(ei + N_EDGES + e0 + i4 * 4);
            atomicAdd(&hist[d4.x >> 6], 1);
            atomicAdd(&hist[d4.y >> 6], 1);
            atomicAdd(&hist[d4.z >> 6], 1);
            atomicAdd(&hist[d4.w >> 6], 1);
        }
        __syncthreads();

        for (int i = tid; i < NB2; i += 512) {
            const int cnt = hist[i];
            hist[i] = (cnt > 0) ? atomicAdd(&gcnt[i], cnt) : 0;
        }
        __syncthreads();

        for (int i4 = tid; i4 < nI4; i4 += 512) {
            const int4 s4 = *(const int4*)(ei + e0 + i4 * 4);
            const int4 d4 = *(const int4*)(ei + N_EDGES + e0 + i4 * 4);
            int b, p;
            b = d4.x >> 6; p = atomicAdd(&hist[b], 1);
            if (p < CAP) sortedG[b * CAP + p] = (s4.x << 6) | (d4.x & 63);
            b = d4.y >> 6; p = atomicAdd(&hist[b], 1);
            if (p < CAP) sortedG[b * CAP + p] = (s4.y << 6) | (d4.y & 63);
            b = d4.z >> 6; p = atomicAdd(&hist[b], 1);
            if (p < CAP) sortedG[b * CAP + p] = (s4.z << 6) | (d4.z & 63);
            b = d4.w >> 6; p = atomicAdd(&hist[b], 1);
            if (p < CAP) sortedG[b * CAP + p] = (s4.w << 6) | (d4.w & 63);
        }
    } else {
        // ---- precompute role: u/w, 2 nodes per wave-iteration ----
        const int lane = tid & 63;
        float w1c[16];
#pragma unroll
        for (int k = 0; k < 16; ++k) w1c[k] = W1[k * 64 + lane];
        const float b1c = b1[lane];

        const int waveId = (bid - SGRID) * 8 + (tid >> 6);
        const int step   = PGRID * 8 * 2;   // 4096 nodes per sweep

        for (int nd = waveId * 2; nd < N_NODES; nd += step) {
            const int nA = nd, nB = nd + 1;  // N_NODES even
            float mA = 0.f, mB = 0.f;
            if (lane < 13) {
                mA = x[nA * 13 + lane];
                mB = x[nB * 13 + lane];
            } else if (lane < 16) {
                mA = pos[nA * 3 + (lane - 13)];
                mB = pos[nB * 3 + (lane - 13)];
            }

            float aA = b1c, wA = 0.f, aB = b1c, wB = 0.f;
#pragma unroll
            for (int k = 0; k < 13; ++k) {
                aA = fmaf(__shfl(mA, k), w1c[k], aA);
                aB = fmaf(__shfl(mB, k), w1c[k], aB);
            }
#pragma unroll
            for (int k = 13; k < 16; ++k) {
                const float pA = __shfl(mA, k), pB = __shfl(mB, k);
                aA = fmaf(pA, w1c[k], aA);  wA = fmaf(pA, w1c[k], wA);
                aB = fmaf(pB, w1c[k], aB);  wB = fmaf(pB, w1c[k], wB);
            }
            u16[nA * 64 + lane] = (_Float16)aA;
            w16[nA * 64 + lane] = (_Float16)wA;
            u16[nB * 64 + lane] = (_Float16)aB;
            w16[nB * 64 + lane] = (_Float16)wB;
        }
    }
}

// ---- k3: bucket aggregate — LDS counting sort + fp16 MFMA register-max ----
__global__ __launch_bounds__(256, 4) void aggregate_kernel(
    const _Float16* __restrict__ u16,  // [N,64] fp16
    const _Float16* __restrict__ w16,  // [N,64] fp16
    const float* __restrict__ W2,      // [64,64]
    const float* __restrict__ b2,      // [64]
    const int*   __restrict__ gcnt,    // [NB2]
    const int*   __restrict__ sortedG, // [NB2][CAP]
    float*       __restrict__ out)     // [N,64]
{
    __shared__ int staged[CAP];         // 5,120 B packed edges
    __shared__ int sortedL[CAP];        // 5,120 B src, grouped by node
    __shared__ int hist[64], nstart[64], hoff[64];

    const int tid  = threadIdx.x;
    const int lane = tid & 63;
    const int wv   = tid >> 6;
    const int q = lane >> 4, n = lane & 15;
    const int b = blockIdx.x;
    const int node0 = b * 64;

    // W2 B-frags (fp16) + bias
    half8 w2f[2][4];
#pragma unroll
    for (int s = 0; s < 2; ++s)
#pragma unroll
        for (int t = 0; t < 4; ++t)
#pragma unroll
            for (int j = 0; j < 8; ++j)
                w2f[s][t][j] = (_Float16)W2[(s * 32 + q * 8 + j) * 64 + (n + 16 * t)];
    float b2c[4];
#pragma unroll
    for (int t = 0; t < 4; ++t) b2c[t] = b2[n + 16 * t];

    if (tid < 64) hist[tid] = 0;
    __syncthreads();

    const int cnt = gcnt[b];
    const int T = cnt < CAP ? cnt : CAP;

    // p2: contiguous slab read -> staged + 64-bin node histogram
    const int nI4 = (T + 3) >> 2;
    for (int i4 = tid; i4 < nI4; i4 += 256) {
        const int4 v = *(const int4*)(sortedG + b * CAP + i4 * 4);
        const int e0 = i4 * 4;
        if (e0 + 0 < T) { staged[e0 + 0] = v.x; atomicAdd(&hist[v.x & 63], 1); }
        if (e0 + 1 < T) { staged[e0 + 1] = v.y; atomicAdd(&hist[v.y & 63], 1); }
        if (e0 + 2 < T) { staged[e0 + 2] = v.z; atomicAdd(&hist[v.z & 63], 1); }
        if (e0 + 3 < T) { staged[e0 + 3] = v.w; atomicAdd(&hist[v.w & 63], 1); }
    }
    __syncthreads();

    // p3: scan hist(64) by wave 0 -> nstart; counting-sort into sortedL
    if (wv == 0) {
        const int v = hist[lane];
        const int inc = wave_incl_scan(v, lane);
        nstart[lane] = inc - v;
        hoff[lane]   = inc - v;
    }
    __syncthreads();
    for (int i = tid; i < T; i += 256) {
        const int w = staged[i];
        const int p = atomicAdd(&hoff[w & 63], 1);
        sortedL[p] = w >> 6;
    }
    __syncthreads();

    // p4: per-node register-max fp16 MFMA (pairs; gathers in flight first)
    const half8 zero8 = {0, 0, 0, 0, 0, 0, 0, 0};

    auto compute = [&](int node, int2 sd, int src,
                       half8 ulo, half8 uhi, half8 wl, half8 wh) {
        float vmax[4] = {0.f, 0.f, 0.f, 0.f};  // 0-init == relu + empty=0
        int base = 0;
        while (true) {
            const int rows = (sd.y - base) < 16 ? (sd.y - base) : 16;
            if (rows > 0) {
                // packed: v_pk_add_f16 (sub) + v_pk_max_f16 (relu)
                const half8 alo = __builtin_elementwise_max(ulo - wl, zero8);
                const half8 ahi = __builtin_elementwise_max(uhi - wh, zero8);
                float4v c2[4];
#pragma unroll
                for (int t = 0; t < 4; ++t) {
                    c2[t] = __builtin_amdgcn_mfma_f32_16x16x32_f16(
                        alo, w2f[0][t], (float4v){0.f, 0.f, 0.f, 0.f}, 0, 0, 0);
                    c2[t] = __builtin_amdgcn_mfma_f32_16x16x32_f16(
                        ahi, w2f[1][t], c2[t], 0, 0, 0);
                }
#pragma unroll
                for (int r = 0; r < 4; ++r) {
                    const int row = q * 4 + r;
#pragma unroll
                    for (int t = 0; t < 4; ++t) {
                        const float v = c2[t][r] + b2c[t];
                        if (row < rows) vmax[t] = fmaxf(vmax[t], v);
                    }
                }
            }
            base += 16;
            if (base >= sd.y) break;
            const int r2 = (sd.y - base) < 16 ? (sd.y - base) : 16;
            src = (n < r2) ? sortedL[sd.x + base + n] : 0;
            ulo = *(const half8*)(u16 + src * 64 + q * 8);
            uhi = *(const half8*)(u16 + src * 64 + 32 + q * 8);
        }
#pragma unroll
        for (int t = 0; t < 4; ++t) {
            vmax[t] = fmaxf(vmax[t], __shfl_xor(vmax[t], 16));
            vmax[t] = fmaxf(vmax[t], __shfl_xor(vmax[t], 32));
        }
        float v = vmax[0];
        v = (q == 1) ? vmax[1] : v;
        v = (q == 2) ? vmax[2] : v;
        v = (q == 3) ? vmax[3] : v;
        if (node < N_NODES) out[node * 64 + lane] = v;
    };

    const int nlbase = wv * 16;
#pragma unroll 1
    for (int g = 0; g < 16; g += 2) {
        const int nlA = nlbase + g, nlB = nlA + 1;
        const int nA = node0 + nlA, nB = node0 + nlB;
        const int2 sdA = {nstart[nlA], hist[nlA]};
        const int2 sdB = {nstart[nlB], hist[nlB]};
        const int nAc = nA < (N_NODES - 1) ? nA : (N_NODES - 1);  // clamp loads
        const int nBc = nB < (N_NODES - 1) ? nB : (N_NODES - 1);

        const int rA = sdA.y < 16 ? sdA.y : 16;
        const int rB = sdB.y < 16 ? sdB.y : 16;
        const int srcA = (n < rA) ? sortedL[sdA.x + n] : 0;
        const int srcB = (n < rB) ? sortedL[sdB.x + n] : 0;

        // both nodes' gathers in flight before either compute
        const half8 ulA = *(const half8*)(u16 + srcA * 64 + q * 8);
        const half8 uhA = *(const half8*)(u16 + srcA * 64 + 32 + q * 8);
        const half8 wlA = *(const half8*)(w16 + nAc * 64 + q * 8);
        const half8 whA = *(const half8*)(w16 + nAc * 64 + 32 + q * 8);
        const half8 ulB = *(const half8*)(u16 + srcB * 64 + q * 8);
        const half8 uhB = *(const half8*)(u16 + srcB * 64 + 32 + q * 8);
        const half8 wlB = *(const half8*)(w16 + nBc * 64 + q * 8);
        const half8 whB = *(const half8*)(w16 + nBc * 64 + 32 + q * 8);

        compute(nA, sdA, srcA, ulA, uhA, wlA, whA);
        compute(nB, sdB, srcB, ulB, uhB, wlB, whB);
    }
}

extern "C" void kernel_launch(void* const* d_in, const int* in_sizes, int n_in,
                              void* d_out, int out_size, void* d_ws, size_t ws_size,
                              hipStream_t stream) {
    const float* x   = (const float*)d_in[0];
    const float* pos = (const float*)d_in[1];
    const float* W1  = (const float*)d_in[2];
    const float* b1  = (const float*)d_in[3];
    const float* W2  = (const float*)d_in[4];
    const float* b2  = (const float*)d_in[5];
    const int*   ei  = (const int*)d_in[6];

    char* ws = (char*)d_ws;
    int* gcnt    = (int*)(ws + 0);              // 6,252 B (padded to 8,192)
    int* sortedG = (int*)(ws + 8192);           // 8,002,560 B [NB2][CAP]
    _Float16* u16 = (_Float16*)(ws + 8010752);  // 12.8 MB
    _Float16* w16 = (_Float16*)(ws + 20810752); // 12.8 MB  (end ~33.6 MB)

    hipMemsetAsync(gcnt, 0, NB2 * sizeof(int), stream);
    prep_kernel<<<SGRID + PGRID, 512, 0, stream>>>(
        x, pos, W1, b1, ei, gcnt, sortedG, u16, w16);
    aggregate_kernel<<<NB2, 256, 0, stream>>>(
        u16, w16, W2, b2, gcnt, sortedG, (float*)d_out);
}